// Round 3
// baseline (92.139 us; speedup 1.0000x reference)
//
#include <hip/hip_runtime.h>
#include <hip/hip_bf16.h>

#define H_ 256
#define W_ 256
#define C_ 128
#define NBPOS 1024   // N * 16 * 16 block positions
#define NACT 512

typedef __bf16 bf16x8 __attribute__((ext_vector_type(8)));
typedef float f32x4 __attribute__((ext_vector_type(4)));

// workspace layout (bytes)
#define SCALE_OFF 294912
#define SHIFT_OFF 295424
#define FLAGS_OFF 295936

// Fused prep: weight repack fp32 HWIO -> bf16 [tap][cin8][cout][8] (blocks 0..575),
// BN fold + flag set (block 576; flags pre-cleared via hipMemsetAsync).
__global__ void prep_kernel(const float* __restrict__ w, const float* __restrict__ b,
                            const float* __restrict__ gamma, const float* __restrict__ beta,
                            const float* __restrict__ mean, const float* __restrict__ var,
                            const int* __restrict__ active,
                            __bf16* __restrict__ wprep, float* __restrict__ scale,
                            float* __restrict__ shift, int* __restrict__ flags) {
  int blk = blockIdx.x, tid = threadIdx.x;
  if (blk < 576) {
    int o = blk * 256 + tid;
    int j = o & 7, cout = (o >> 3) & 127, k8 = (o >> 10) & 15, tap = o >> 14;
    wprep[o] = (__bf16)w[((size_t)tap * 128 + k8 * 8 + j) * 128 + cout];
  } else {
    if (tid < 128) {
      float s = gamma[tid] * rsqrtf(var[tid] + 1e-3f);
      scale[tid] = s;
      shift[tid] = (b[tid] - mean[tid]) * s + beta[tid];
    }
    for (int i = tid; i < NACT; i += 256) flags[active[i]] = 1;
  }
}

// ONE kernel, grid = 1024 position blocks. Inactive -> stream copy (HBM-bound);
// active -> implicit-GEMM conv + BN + ReLU (MFMA-bound). Random actives give a
// natural per-CU mix so HBM stays saturated while MFMA runs.
__global__ __launch_bounds__(256, 2) void fused_kernel(
    const float* __restrict__ x, const __bf16* __restrict__ wprep,
    const float* __restrict__ scale, const float* __restrict__ shift,
    const int* __restrict__ flags, float* __restrict__ y) {
  __shared__ unsigned char ldsA[324 * 128];   // 18*18 spatial x 64ch bf16 (swizzled)
  __shared__ unsigned char ldsB[2][8192];     // ping-pong 32k x 128cout bf16 weight tile

  const int pb = blockIdx.x;
  const int tid = threadIdx.x;
  const int bn = pb >> 8, by = (pb >> 4) & 15, bx = pb & 15;
  const int h0 = by * 16, w0 = bx * 16;

  if (!flags[pb]) {
    // ---- copy path: 16x16x128 fp32 block, float4 streaming ----
    size_t base4 = ((((size_t)bn * H_ + h0) * W_ + w0) * C_) >> 2;
    const float4* __restrict__ xs = (const float4*)x;
    float4* __restrict__ ys = (float4*)y;
#pragma unroll 8
    for (int i = 0; i < 32; ++i) {
      int lin = (i << 8) + tid;
      int row = lin >> 9, rem = lin & 511;
      size_t idx4 = base4 + (size_t)row * (W_ * C_ / 4) + rem;
      ys[idx4] = xs[idx4];
    }
    return;
  }

  // ---- conv path ----
  const int lane = tid & 63;
  const int wid = tid >> 6;
  const float* xb = x + (size_t)bn * (H_ * W_ * C_);

  float sc[8], sh[8];
  {
    int col = lane & 15;
#pragma unroll
    for (int nb = 0; nb < 8; ++nb) {
      sc[nb] = scale[nb * 16 + col];
      sh[nb] = shift[nb * 16 + col];
    }
  }

  f32x4 acc[4][8];
  f32x4 zero = {0.f, 0.f, 0.f, 0.f};
#pragma unroll
  for (int i = 0; i < 4; ++i)
#pragma unroll
    for (int j = 0; j < 8; ++j) acc[i][j] = zero;

  const uint4* wp4 = (const uint4*)wprep;
  uint4 t0, t1;
  auto load_t = [&](int u) {                  // weight tile for flat K-step u
    int ks = u % 18, h = u / 18;
    int tile = ((ks >> 1) << 2) + (h << 1) + (ks & 1);
    t0 = wp4[tile * 512 + tid];
    t1 = wp4[tile * 512 + 256 + tid];
  };
  auto stage = [&](int half) {                // 18x18 x 64ch patch -> bf16 LDS, XOR-swizzled
    for (int chunk = tid; chunk < 324 * 8; chunk += 256) {
      int s = chunk >> 3, c8 = chunk & 7;
      int iy = s / 18, ix = s - iy * 18;
      int hs = h0 + iy, wsp = w0 + ix;
      float4 f0 = make_float4(0.f, 0.f, 0.f, 0.f), f1 = f0;
      if (hs < H_ && wsp < W_) {
        const float* p = xb + (size_t)(hs * W_ + wsp) * C_ + half * 64 + c8 * 8;
        f0 = *(const float4*)p;
        f1 = *(const float4*)(p + 4);
      }
      bf16x8 v;
      v[0] = (__bf16)f0.x; v[1] = (__bf16)f0.y; v[2] = (__bf16)f0.z; v[3] = (__bf16)f0.w;
      v[4] = (__bf16)f1.x; v[5] = (__bf16)f1.y; v[6] = (__bf16)f1.z; v[7] = (__bf16)f1.w;
      int lin = s * 128 + c8 * 16;
      *(bf16x8*)(&ldsA[lin ^ ((s & 7) << 4)]) = v;
    }
  };

  // prologue: stage half 0, write B tile 0 into buf0, prefetch tile 1
  load_t(0);
  stage(0);
  ((uint4*)ldsB[0])[tid] = t0;
  ((uint4*)ldsB[0])[256 + tid] = t1;
  load_t(1);
  __syncthreads();

  const int koff = (lane >> 4) * 16;
  const int colb = (lane & 15) * 16;
  const int krow = (lane >> 4) * 2048;

  // 36 flat K-steps of 32 channels (tap 0..8 x ch-chunk, per 64-ch half),
  // ping-pong ldsB with write-one-ahead: ONE barrier per step.
  for (int u = 0; u < 36; ++u) {
    int cur = u & 1;
    if (u < 35) {
      ((uint4*)ldsB[cur ^ 1])[tid] = t0;        // tile u+1
      ((uint4*)ldsB[cur ^ 1])[256 + tid] = t1;
      if (u < 34) load_t(u + 2);
    }
    int ks = u % 18;
    int tap = ks >> 1, kch = ks & 1;
    int dyv = tap / 3, dxv = tap - dyv * 3;

    bf16x8 a[4];
#pragma unroll
    for (int mi = 0; mi < 4; ++mi) {
      int srow = (wid * 4 + mi + dyv) * 18 + dxv + (lane & 15);
      int lin = srow * 128 + kch * 64 + koff;
      a[mi] = *(const bf16x8*)(&ldsA[lin ^ ((srow & 7) << 4)]);
    }
    bf16x8 bfr[8];
#pragma unroll
    for (int nb = 0; nb < 8; ++nb)
      bfr[nb] = *(const bf16x8*)(&ldsB[cur][krow + nb * 256 + colb]);
#pragma unroll
    for (int mi = 0; mi < 4; ++mi)
#pragma unroll
      for (int nb = 0; nb < 8; ++nb)
        acc[mi][nb] = __builtin_amdgcn_mfma_f32_16x16x32_bf16(a[mi], bfr[nb], acc[mi][nb], 0, 0, 0);

    __syncthreads();                            // step's ldsB[cur] reads done; u+1 writes visible
    if (u == 17) {                              // re-stage ldsA with channel half 1
      stage(1);
      __syncthreads();
    }
  }

  // epilogue: BN + ReLU + scatter. D frag: col=lane&15, row=(lane>>4)*4+reg
  const int colc = lane & 15;
  float* yb = y + (((size_t)bn * H_ + h0) * W_ + w0) * C_;
#pragma unroll
  for (int mi = 0; mi < 4; ++mi) {
    int oy = wid * 4 + mi;
#pragma unroll
    for (int r = 0; r < 4; ++r) {
      int ox = (lane >> 4) * 4 + r;
      float* yr = yb + ((size_t)oy * W_ + ox) * C_;
#pragma unroll
      for (int nb = 0; nb < 8; ++nb) {
        float v = acc[mi][nb][r] * sc[nb] + sh[nb];
        yr[nb * 16 + colc] = fmaxf(v, 0.f);
      }
    }
  }
}

extern "C" void kernel_launch(void* const* d_in, const int* in_sizes, int n_in,
                              void* d_out, int out_size, void* d_ws, size_t ws_size,
                              hipStream_t stream) {
  const float* x     = (const float*)d_in[0];
  const float* w     = (const float*)d_in[1];
  const float* b     = (const float*)d_in[2];
  const float* gamma = (const float*)d_in[3];
  const float* beta  = (const float*)d_in[4];
  const float* mean  = (const float*)d_in[5];
  const float* var   = (const float*)d_in[6];
  const int*   act   = (const int*)d_in[7];
  float* y = (float*)d_out;
  char* ws = (char*)d_ws;
  __bf16* wprep = (__bf16*)ws;
  float* scale = (float*)(ws + SCALE_OFF);
  float* shift = (float*)(ws + SHIFT_OFF);
  int* flags = (int*)(ws + FLAGS_OFF);

  hipMemsetAsync(flags, 0, NBPOS * sizeof(int), stream);
  prep_kernel<<<dim3(577), dim3(256), 0, stream>>>(w, b, gamma, beta, mean, var, act,
                                                   wprep, scale, shift, flags);
  fused_kernel<<<dim3(NBPOS), dim3(256), 0, stream>>>(x, wprep, scale, shift, flags, y);
}